// Round 10
// baseline (1576.530 us; speedup 1.0000x reference)
//
#include <hip/hip_runtime.h>
#include <hip/hip_bf16.h>

// Problem constants (bert-base captioning decoder)
#define VCB 30522   // vocab
#define EMB 512     // embed size
#define ATTD 512    // attention dim
#define ENC 2048    // encoder dim
#define HD 512      // hidden dim
#define BB 32       // batch
#define NF 49       // image features
#define TSTEPS 20   // decode steps
#define EIN 2560    // EMB + ENC (lstm input)
#define KCAT 3072   // EIN + HD (fused gate GEMM K)
#define WSTRIDE 3080 // padded LDS row stride (bf16) -> row-to-row bank shift of 4
#define DTPB 512    // k_decode threads per block (8 waves)
#define NBLK 128    // k_decode blocks: each owns 4 hidden cols (16 wcat rows)

typedef __attribute__((ext_vector_type(8))) __bf16 bf16x8;
typedef __attribute__((ext_vector_type(4))) __bf16 bf16x4;
typedef __attribute__((ext_vector_type(4))) float floatx4;
typedef __hip_bfloat16 bf16;

__device__ __forceinline__ float bf2f(bf16 x){ return __bfloat162float(x); }
__device__ __forceinline__ bf16 f2bf(float x){ return __float2bfloat16(x); }
__device__ __forceinline__ float sigm(float x){ return 1.0f/(1.0f+expf(-x)); }
// fast tanh: (e^{2x}-1)/(e^{2x}+1) via hardware exp + rcp. |err| ~1e-6.
__device__ __forceinline__ float fast_tanh(float x){
    float e2 = __expf(2.0f*x);
    return 1.0f - 2.0f*__builtin_amdgcn_rcpf(e2 + 1.0f);
}

// ---- coherent (Infinity-Cache point) relaxed dword access -----------------
__device__ __forceinline__ unsigned coh_ld(const unsigned* p){
    return __hip_atomic_load(p, __ATOMIC_RELAXED, __HIP_MEMORY_SCOPE_AGENT);
}
__device__ __forceinline__ void coh_st(unsigned* p, unsigned v){
    __hip_atomic_store(p, v, __ATOMIC_RELAXED, __HIP_MEMORY_SCOPE_AGENT);
}
__device__ __forceinline__ unsigned pack2bf(float a, float b){
    unsigned short ua = __builtin_bit_cast(unsigned short, f2bf(a));
    unsigned short ub = __builtin_bit_cast(unsigned short, f2bf(b));
    return (unsigned)ua | ((unsigned)ub << 16);
}

// ---- one-way producer->consumer flags + two-tier burn-wait (r9) -----------
// r3..r7: every sync protocol = ~22us/rendezvous. Surviving theories:
// T1 DVFS (chip ~97% idle -> clocks floor -> all latencies x5-10; prior spins
// too narrow to raise aggregate activity) and T2 (phase-B sc1-load chain).
// r9: EVERY thread busy-burns (DVFS pin) but only WAVE 0 polls the global
// flag (1 outstanding MALL load per block -- avoids a 1024-wave same-line
// polling storm); wave 0 publishes the detected epoch to an LDS flag that
// waves 1-7 poll (CU-local, zero fabric traffic).
// gpost: __syncthreads drains vmcnt(0) (all sc1 stores AND loads ACKed at
// the coherent point) before tid0's relaxed add becomes visible.
__device__ __forceinline__ void gpost(unsigned* ctr){
    __syncthreads();
    if (threadIdx.x == 0)
        __hip_atomic_fetch_add(ctr, 1u, __ATOMIC_RELAXED, __HIP_MEMORY_SCOPE_AGENT);
}
__device__ __forceinline__ void gwait(const unsigned* ctr, unsigned tgt,
                                      volatile unsigned* sflag){
    float x = 1.0f;
    if (threadIdx.x < 64){
        while (coh_ld(ctr) < tgt){
#pragma unroll
            for (int i = 0; i < 8; ++i)
                x = __builtin_fmaf(x, 1.0000001f, 1e-12f);
        }
        if (threadIdx.x == 0) *sflag = tgt;       // LDS publish
    } else {
        while (*sflag < tgt){                     // LDS poll, no fabric traffic
#pragma unroll
            for (int i = 0; i < 32; ++i)
                x = __builtin_fmaf(x, 1.0000001f, 1e-12f);
        }
    }
    asm volatile("" :: "v"(x));
    __syncthreads();
}

// ---- dtype-adaptive load/store helpers (f=1: data is f32; f=0: bf16) ------
__device__ __forceinline__ float ld1(const void* base, size_t idx, int f){
    if (f) return ((const float*)base)[idx];
    return bf2f(((const bf16*)base)[idx]);
}
__device__ __forceinline__ bf16x8 ldbf8(const void* base, size_t idx, int f){
    if (f){
        const float* p = (const float*)base + idx;
        float4 a = *(const float4*)p, b = *(const float4*)(p+4);
        bf16x8 r;
        r[0]=(__bf16)a.x; r[1]=(__bf16)a.y; r[2]=(__bf16)a.z; r[3]=(__bf16)a.w;
        r[4]=(__bf16)b.x; r[5]=(__bf16)b.y; r[6]=(__bf16)b.z; r[7]=(__bf16)b.w;
        return r;
    }
    return *(const bf16x8*)((const bf16*)base + idx);
}
__device__ __forceinline__ bf16x8 bf8_of_f32(const float* p){
    float4 a = *(const float4*)p, b = *(const float4*)(p+4);
    bf16x8 r;
    r[0]=(__bf16)a.x; r[1]=(__bf16)a.y; r[2]=(__bf16)a.z; r[3]=(__bf16)a.w;
    r[4]=(__bf16)b.x; r[5]=(__bf16)b.y; r[6]=(__bf16)b.z; r[7]=(__bf16)b.w;
    return r;
}
__device__ __forceinline__ void st1(void* base, size_t idx, float v, int f){
    if (f) ((float*)base)[idx] = v;
    else   ((bf16*)base)[idx] = f2bf(v);
}

#define MFMA16(a,b,c) __builtin_amdgcn_mfma_f32_16x16x32_bf16(a,b,c,0,0,0)
// Verified fragment layout (learn_hip m89/m91):
//   A: lane holds A[m=lane&15][k=(lane>>4)*8+j]   (row-major [M][K])
//   B: lane holds Bt[n=lane&15][k=(lane>>4)*8+j]  (row-major [N][K])
//   D: lane holds D[row=(lane>>4)*4+r][col=lane&15]

// ---------------- kernel 0: dtype detect + flag zero -----------------------
__global__ void k_detect(const void* emb, int* flag, unsigned* bar){
    int tid = threadIdx.x;
    __shared__ int bad;
    if (tid == 0) bad = 0;
    for (int i = tid; i < 1024; i += 256) bar[i] = 0u;
    __syncthreads();
    const unsigned short* u = (const unsigned short*)emb;
    int local = 0;
    for (int i = tid; i < 4096; i += 256){
        int e = (u[i] >> 7) & 0xFF;
        if (e > 140) local = 1;           // |v| > 2^13: impossible for real data
    }
    if (local) bad = 1;
    __syncthreads();
    if (tid == 0) *flag = bad;
}

// ---------------- prep kernels: convert weights to bf16 once ---------------
// wcat[r][0..2559] = w_ih[r], wcat[r][2560..3071] = w_hh[r]   (r = gate*512+n)
__global__ void k_prep_gates(const void* w_ih, const void* w_hh, bf16* __restrict__ wcat,
                             const int* __restrict__ flag){
    int ff = *flag;
    int r = blockIdx.x, tid = threadIdx.x;
    for (int i = tid*8; i < KCAT; i += 2048){
        bf16x8 v;
        if (i + 8 <= EIN){
            v = ldbf8(w_ih, (size_t)r*EIN + i, ff);
        } else if (i >= EIN){
            v = ldbf8(w_hh, (size_t)r*HD + (i - EIN), ff);
        } else {
#pragma unroll
            for (int j = 0; j < 8; ++j){
                int k = i + j;
                v[j] = (__bf16)((k < EIN) ? ld1(w_ih, (size_t)r*EIN + k, ff)
                                          : ld1(w_hh, (size_t)r*HD + (k - EIN), ff));
            }
        }
        *(bf16x8*)(wcat + (size_t)r*KCAT + i) = v;
    }
}
// vectorized convert, n must be divisible by 8
__global__ void k_prep_cvt8(const void* src, bf16* __restrict__ dst, size_t n8,
                            const int* __restrict__ flag){
    int ff = *flag;
    size_t idx = (size_t)blockIdx.x*256 + threadIdx.x;
    size_t stride = (size_t)gridDim.x*256;
    for (size_t i = idx; i < n8; i += stride)
        *(bf16x8*)(dst + i*8) = ldbf8(src, i*8, ff);
}

// ---------------- kernel 1: mean over feature positions (f32 out) ----------
__global__ void k_mean(const void* feat, float* __restrict__ mean_f,
                       const int* __restrict__ flag){
    int ff = *flag;
    int b = blockIdx.x, tid = threadIdx.x;
    for (int i = 0; i < ENC/256; ++i){
        int e = i*256 + tid;
        size_t base = (size_t)b*NF*ENC + e;
        float s = 0.f;
        for (int n = 0; n < NF; ++n) s += ld1(feat, base + (size_t)n*ENC, ff);
        mean_f[b*ENC + e] = s * (1.0f/49.0f);
    }
}

// ---------------- kernel 2: h0/c0 = mean_f @ [ihw|icw]^T + b (MFMA) --------
__global__ void k_init_hc(const float* __restrict__ mean_f,
                          const void* ihw, const void* ihb,
                          const void* icw, const void* icb,
                          float* __restrict__ Hbuf, float* __restrict__ c_f32,
                          const int* __restrict__ flag){
    int ff = *flag;
    int tid = threadIdx.x, wave = tid>>6, lane = tid&63, quad = lane>>4, lq = lane&15;
    int n0 = blockIdx.x*16;
    int ng = n0 + lq;
    const void* w = (ng < HD) ? ihw : icw;
    size_t wrow = (size_t)(ng < HD ? ng : ng - HD)*ENC;
    floatx4 acc[2] = {{0,0,0,0},{0,0,0,0}};
    int kb = wave*512;
    for (int kk = 0; kk < 16; ++kk){
        int k = kb + kk*32 + quad*8;
        bf16x8 bfr = ldbf8(w, wrow + k, ff);
#pragma unroll
        for (int mt = 0; mt < 2; ++mt){
            bf16x8 afr = bf8_of_f32(mean_f + (size_t)(mt*16+lq)*ENC + k);
            acc[mt] = MFMA16(afr, bfr, acc[mt]);
        }
    }
    __shared__ float red[4][2][16][16];
#pragma unroll
    for (int mt = 0; mt < 2; ++mt)
        for (int r = 0; r < 4; ++r)
            red[wave][mt][quad*4+r][lq] = acc[mt][r];
    __syncthreads();
    for (int rep = 0; rep < 2; ++rep){
        int idx = rep*256 + tid;
        int mt = idx>>8, mm = (idx>>4)&15, nn = idx&15;
        float v = red[0][mt][mm][nn]+red[1][mt][mm][nn]+red[2][mt][mm][nn]+red[3][mt][mm][nn];
        int n_g = n0 + nn, b = mt*16 + mm;
        if (n_g < HD) Hbuf[b*HD + n_g]        = v + ld1(ihb, n_g, ff);
        else          c_f32[b*HD + (n_g-HD)]  = v + ld1(icb, n_g - HD, ff);
    }
}

// ---------------- kernel 3: u_hs = feat_bf @ U_w^T + U_b (MFMA, f32 out) ---
__global__ void k_uhs(const bf16* __restrict__ feat_bf, const void* U_w, const void* U_b,
                      float* __restrict__ u_hs, const int* __restrict__ flag){
    int ff = *flag;
    int tid = threadIdx.x, wave = tid>>6, lane = tid&63, quad = lane>>4, lq = lane&15;
    int m0 = blockIdx.x*16;
    int n0 = blockIdx.y*64 + wave*16;
    size_t arow = (size_t)(m0+lq)*ENC;
    size_t brow = (size_t)(n0+lq)*ENC;
    floatx4 acc = {0,0,0,0};
    for (int kk = 0; kk < ENC/32; ++kk){
        int k = kk*32 + quad*8;
        bf16x8 afr = *(const bf16x8*)(feat_bf + arow + k);
        bf16x8 bfr = ldbf8(U_w,  brow + k, ff);
        acc = MFMA16(afr, bfr, acc);
    }
    float ub = ld1(U_b, n0+lq, ff);
    for (int r = 0; r < 4; ++r){
        int m = m0 + quad*4 + r;
        u_hs[(size_t)m*ATTD + n0 + lq] = acc[r] + ub;
    }
}

// ---------------- kernel 4: persistent cooperative decode loop -------------
// Grid 128 x 512 threads. Block bid owns hidden cols {4bid..4bid+3}: its 16
// wcat rows (98.5 KB) live in LDS for the whole loop; its c state in LDS.
// Cross-block data (lstm_in, Hbuf) via relaxed agent-scope (sc1) dwords.
// Sync = two one-way flag waves per step; two-tier burn-wait (wave 0 polls
// global, waves 1-7 poll LDS, all burn FMAs -> DVFS pin without MALL storm).
// Phase B K-split over ALL 8 waves (384 each) -> halves the exposed
// sc1-load chain per wave (attacks T2).
__global__ void __launch_bounds__(DTPB) k_decode(
        float* __restrict__ Hbuf, const float* __restrict__ c0_f32,
        const bf16* __restrict__ Ww_bf, const void* __restrict__ W_b,
        const float* __restrict__ u_hs, const void* __restrict__ A_w,
        const void* __restrict__ A_b, const int* __restrict__ captions,
        const void* __restrict__ emb, const bf16* __restrict__ feat_bf,
        bf16* __restrict__ lstm_in, const bf16* __restrict__ wcat,
        const void* __restrict__ b_ih, const void* __restrict__ b_hh,
        bf16* __restrict__ Hall_bf, void* __restrict__ d_out,
        const int* __restrict__ flag, unsigned* __restrict__ bar)
{
    const int ff = *flag;
    const int bid = blockIdx.x, tid = threadIdx.x;
    const int wave = tid>>6, lane = tid&63, quad = lane>>4, lq = lane&15;

    __shared__ bf16  wlds[16*WSTRIDE];  // 98.56 KB: this block's 16 wcat rows
    __shared__ float ubuf[4096];        // 16 KB: attn scratch UNION mfma red[8]
    __shared__ float aw_s[ATTD];        // 2 KB (attention blocks only)
    __shared__ float c_loc[BB*4];       // persistent c state (32 b x 4 cols)
    __shared__ float gbias[16];         // b_ih+b_hh for this block's 16 rows
    __shared__ unsigned sflag1, sflag2; // LDS epoch mirrors for two-tier wait

    unsigned* lin_u = (unsigned*)lstm_in;     // lstm_in as dwords (bf16 pairs)
    unsigned* flag1 = bar;                    // attention-done
    unsigned* flag2 = bar + 64;               // h-published

    if (tid == 0){ sflag1 = 0u; sflag2 = 0u; }

    // ---- prologue: load persistent state ----
    for (int n = 0; n < 16; ++n){
        int g = n>>2, j = n&3;
        const bf16* src = wcat + (size_t)(g*HD + (bid<<2) + j)*KCAT;
        for (int c8 = tid; c8 < KCAT/8; c8 += DTPB)
            *(bf16x8*)(wlds + n*WSTRIDE + c8*8) = *(const bf16x8*)(src + c8*8);
    }
    if (tid < 128){
        int bb = tid&31, j = tid>>5, col = (bid<<2)+j;
        c_loc[bb*4+j] = c0_f32[bb*HD + col];   // plain: pre-kernel data
    }
    if (tid < 64){
        // h-section of lstm_in for t=0 (h0 from Hbuf slot 0), dword-packed
        int bb = tid&31, j2 = tid>>5;
        int c0 = (bid<<2) + 2*j2;
        float h0 = Hbuf[bb*HD + c0], h1 = Hbuf[bb*HD + c0 + 1];
        coh_st(lin_u + (size_t)bb*(KCAT/2) + (EIN + c0)/2, pack2bf(h0, h1));
    }
    if (tid < 16){
        int g = tid>>2, j = tid&3, col = (bid<<2)+j;
        gbias[tid] = ld1(b_ih, g*HD+col, ff) + ld1(b_hh, g*HD+col, ff);
    }
    if (bid < BB)
        for (int i = tid; i < ATTD; i += DTPB) aw_s[i] = ld1(A_w, i, ff);
    gpost(flag2);                       // publish #0 (h0 section written)

    // union views of ubuf (phase A scratch vs phase B reduce — never live
    // at the same time; flag waits + __syncthreads order every transition)
    float* h_sh    = ubuf;          // [512]
    float* wah_s   = ubuf + 512;    // [512]
    float* sc_s    = ubuf + 1024;   // [52]
    float* alpha_s = ubuf + 1088;   // [52]
    float (*red)[2][16][16] = (float (*)[2][16][16])ubuf;  // [8][2][16][16]

    for (int t = 0; t < TSTEPS; ++t){
        // ===== phase A: attention (one block per batch b) =====
        if (bid < BB){
            gwait(flag2, 128u*(unsigned)(t+1), &sflag2);
            const int b = bid;
            const unsigned* hrow = (const unsigned*)(Hbuf + (size_t)t*BB*HD + b*HD);
            for (int i = tid; i < HD; i += DTPB)
                h_sh[i] = __uint_as_float(coh_ld(hrow + i));
            int cap = captions[b*21 + t];
            for (int e2 = tid; e2 < EMB/2; e2 += DTPB){
                float a = ld1(emb, (size_t)cap*EMB + 2*e2,     ff);
                float c = ld1(emb, (size_t)cap*EMB + 2*e2 + 1, ff);
                coh_st(lin_u + (size_t)b*(KCAT/2) + e2, pack2bf(a, c));
            }
            __syncthreads();
            // w_ah[a] = h . W_w[a] + W_b[a]  (1 row/thread, 4 split accs)
            for (int a = tid; a < ATTD; a += DTPB){
                const bf16* wr = Ww_bf + (size_t)a*HD;
                float s0=0.f, s1=0.f, s2=0.f, s3=0.f;
                for (int k = 0; k < HD; k += 8){
                    bf16x8 wv = *(const bf16x8*)(wr + k);
                    s0 += (float)wv[0]*h_sh[k+0] + (float)wv[4]*h_sh[k+4];
                    s1 += (float)wv[1]*h_sh[k+1] + (float)wv[5]*h_sh[k+5];
                    s2 += (float)wv[2]*h_sh[k+2] + (float)wv[6]*h_sh[k+6];
                    s3 += (float)wv[3]*h_sh[k+3] + (float)wv[7]*h_sh[k+7];
                }
                wah_s[a] = ((s0+s1)+(s2+s3)) + ld1(W_b, a, ff);
            }
            __syncthreads();
            // scores[n] = A_w . tanh(u_hs[b,n,:] + w_ah) + A_b  (8 waves)
            {
                int a0 = lane*8;
                for (int n = wave; n < NF; n += 8){
                    const float* up = u_hs + (size_t)(b*NF + n)*ATTD + a0;
                    float4 u0 = *(const float4*)up;
                    float4 u1 = *(const float4*)(up + 4);
                    float p0 = fast_tanh(u0.x + wah_s[a0+0])*aw_s[a0+0]
                             + fast_tanh(u0.y + wah_s[a0+1])*aw_s[a0+1]
                             + fast_tanh(u0.z + wah_s[a0+2])*aw_s[a0+2]
                             + fast_tanh(u0.w + wah_s[a0+3])*aw_s[a0+3];
                    float p1 = fast_tanh(u1.x + wah_s[a0+4])*aw_s[a0+4]
                             + fast_tanh(u1.y + wah_s[a0+5])*aw_s[a0+5]
                             + fast_tanh(u1.z + wah_s[a0+6])*aw_s[a0+6]
                             + fast_tanh(u1.w + wah_s[a0+7])*aw_s[a0+7];
                    float p = p0 + p1;
                    for (int off = 32; off; off >>= 1) p += __shfl_down(p, off);
                    if (lane == 0) sc_s[n] = p + ld1(A_b, 0, ff);
                }
            }
            __syncthreads();
            // softmax over 49 (wave 0) + alpha output
            if (wave == 0){
                float v = (lane < NF) ? sc_s[lane] : -1e30f;
                float mx = v;
                for (int off = 32; off; off >>= 1) mx = fmaxf(mx, __shfl_down(mx, off));
                mx = __shfl(mx, 0);
                float e = (lane < NF) ? expf(v - mx) : 0.f;
                float s = e;
                for (int off = 32; off; off >>= 1) s += __shfl_down(s, off);
                s = __shfl(s, 0);
                if (lane < NF){
                    float al = e / s;
                    alpha_s[lane] = al;
                    st1(d_out, (size_t)BB*TSTEPS*VCB + (size_t)b*(TSTEPS*NF) + t*NF + lane, al, ff);
                }
            }
            __syncthreads();
            // context[e] = sum_n alpha[n]*feat_bf[b,n,e]; thread owns 4 contig e
            {
                int e0 = tid*4;
                float acc[4] = {0,0,0,0};
#pragma unroll 7
                for (int n = 0; n < NF; ++n){
                    float al = alpha_s[n];
                    bf16x4 v = *(const bf16x4*)(feat_bf + (size_t)b*NF*ENC + (size_t)n*ENC + e0);
#pragma unroll
                    for (int j = 0; j < 4; ++j) acc[j] += al*(float)v[j];
                }
                unsigned* lrow = lin_u + (size_t)b*(KCAT/2) + (EMB + e0)/2;
                coh_st(lrow,     pack2bf(acc[0], acc[1]));
                coh_st(lrow + 1, pack2bf(acc[2], acc[3]));
            }
            gpost(flag1);               // ctx(t) published
        }
        gwait(flag1, 32u*(unsigned)(t+1), &sflag1);  // lstm_in(t) complete

        // ===== phase B: gates MFMA (LDS wcat, ALL 8 waves) + LSTM pointwise =
        {
            int kb = wave*384;                      // K split 8x384 over waves
            floatx4 acc0 = {0,0,0,0}, acc1 = {0,0,0,0};
            const bf16* wrow = wlds + (size_t)lq*WSTRIDE;  // 16 distinct B-rows
            const unsigned* ar0 = lin_u + (size_t)lq*(KCAT/2);
            const unsigned* ar1 = lin_u + (size_t)(16+lq)*(KCAT/2);
            union U8 { unsigned u[4]; bf16x8 v; };
#pragma unroll
            for (int kk = 0; kk < 12; ++kk){
                int kd = (kb + kk*32 + quad*8) >> 1;   // dword index
                bf16x8 bfr = *(const bf16x8*)(wrow + kb + kk*32 + quad*8);
                U8 a0, a1;
#pragma unroll
                for (int q = 0; q < 4; ++q){
                    a0.u[q] = coh_ld(ar0 + kd + q);
                    a1.u[q] = coh_ld(ar1 + kd + q);
                }
                acc0 = MFMA16(a0.v, bfr, acc0);
                acc1 = MFMA16(a1.v, bfr, acc1);
            }
#pragma unroll
            for (int r = 0; r < 4; ++r){
                red[wave][0][quad*4+r][lq] = acc0[r];
                red[wave][1][quad*4+r][lq] = acc1[r];
            }
        }
        __syncthreads();
        if (tid < 64){
            int bb = tid&31, j2 = tid>>5;           // j2: col pair 0/1
            int mt = bb>>4, mm = bb&15;
            float hn[2];
#pragma unroll
            for (int sub = 0; sub < 2; ++sub){
                int j = 2*j2 + sub;                 // col-in-block 0..3
                float G[4];
#pragma unroll
                for (int g = 0; g < 4; ++g){
                    int n = g*4 + j;                // B-row n = gate*4 + col
                    float s = 0.f;
#pragma unroll
                    for (int w8 = 0; w8 < 8; ++w8) s += red[w8][mt][mm][n];
                    G[g] = s + gbias[n];
                }
                float c_old = c_loc[bb*4+j];
                float c_new = sigm(G[1])*c_old + sigm(G[0])*tanhf(G[2]);
                float h_new = sigm(G[3])*tanhf(c_new);
                c_loc[bb*4+j] = c_new;
                hn[sub] = h_new;
            }
            int colb = (bid<<2) + 2*j2;
            unsigned* hb = (unsigned*)(Hbuf + (size_t)(t+1)*BB*HD + bb*HD + colb);
            coh_st(hb,     __float_as_uint(hn[0]));
            coh_st(hb + 1, __float_as_uint(hn[1]));
            ((unsigned*)Hall_bf)[((size_t)t*BB*HD + bb*HD + colb) >> 1] = pack2bf(hn[0], hn[1]);
            coh_st(lin_u + (size_t)bb*(KCAT/2) + (EIN + colb)/2, pack2bf(hn[0], hn[1]));
        }
        gpost(flag2);                   // h(t+1) published (+ B(t) reads done)
    }
}

// ---------------- kernel 6: preds = Hall_bf @ fcnw_bf^T + fcn_b ------------
__global__ void __launch_bounds__(256) k_fcn(const bf16* __restrict__ Hall_bf,
                                             const bf16* __restrict__ fcnw_bf,
                                             const void* fcn_b, void* d_out,
                                             const int* __restrict__ flag){
    int ff = *flag;
    int tid = threadIdx.x, wave = tid>>6, lane = tid&63, quad = lane>>4, lq = lane&15;
    int n0 = blockIdx.x*64 + wave*16;
    int v = n0 + lq;
    int vc = (v < VCB) ? v : (VCB-1);
    const bf16* brow = fcnw_bf + (size_t)vc*HD;
    bf16x8 bfr[16];
#pragma unroll
    for (int kk = 0; kk < 16; ++kk) bfr[kk] = *(const bf16x8*)(brow + kk*32 + quad*8);
    float bias = ld1(fcn_b, vc, ff);
    for (int mt = 0; mt < 40; ++mt){
        const bf16* arow = Hall_bf + (size_t)(mt*16 + lq)*HD;
        floatx4 acc = {0,0,0,0};
#pragma unroll
        for (int kk = 0; kk < 16; ++kk){
            bf16x8 afr = *(const bf16x8*)(arow + kk*32 + quad*8);
            acc = MFMA16(afr, bfr[kk], acc);
        }
        if (v < VCB){
#pragma unroll
            for (int r = 0; r < 4; ++r){
                int m = mt*16 + quad*4 + r;
                int b = m & 31, tt = m >> 5;
                st1(d_out, (size_t)b*(TSTEPS*VCB) + (size_t)tt*VCB + v, acc[r] + bias, ff);
            }
        }
    }
}

// ---------------- host launch ---------------------------------------------
extern "C" void kernel_launch(void* const* d_in, const int* in_sizes, int n_in,
                              void* d_out, int out_size, void* d_ws, size_t ws_size,
                              hipStream_t stream) {
    const void* feat  = d_in[0];
    const int*  caps  = (const int*)d_in[1];
    const void* emb   = d_in[2];
    const void* W_w   = d_in[3];
    const void* W_b   = d_in[4];
    const void* U_w   = d_in[5];
    const void* U_b   = d_in[6];
    const void* A_w   = d_in[7];
    const void* A_b   = d_in[8];
    const void* ihw   = d_in[9];
    const void* ihb   = d_in[10];
    const void* icw   = d_in[11];
    const void* icb   = d_in[12];
    const void* w_ih  = d_in[13];
    const void* w_hh  = d_in[14];
    const void* b_ih  = d_in[15];
    const void* b_hh  = d_in[16];
    const void* fcn_w = d_in[17];
    const void* fcn_b = d_in[18];

    // workspace layout (16B-aligned)
    char* ws = (char*)d_ws;
    size_t off = 0;
    float* u_hs    = (float*)(ws + off); off += (size_t)BB*NF*ATTD*4;       // 3.2 MB
    float* c_f32   = (float*)(ws + off); off += (size_t)BB*HD*4;            // 64 KB
    float* mean_f  = (float*)(ws + off); off += (size_t)BB*ENC*4;           // 256 KB
    float* Hbuf    = (float*)(ws + off); off += (size_t)(TSTEPS+1)*BB*HD*4; // 1.38 MB
    bf16*  lstm_in = (bf16*) (ws + off); off += (size_t)BB*KCAT*2;          // 192 KB
    bf16*  Hall_bf = (bf16*) (ws + off); off += (size_t)TSTEPS*BB*HD*2;     // 640 KB
    bf16*  wcat    = (bf16*) (ws + off); off += (size_t)4*HD*KCAT*2;        // 12.6 MB
    bf16*  fcnw_bf = (bf16*) (ws + off); off += (size_t)VCB*HD*2;           // 31.25 MB
    bf16*  Ww_bf   = (bf16*) (ws + off); off += (size_t)ATTD*HD*2;          // 512 KB
    bf16*  feat_bf = (bf16*) (ws + off); off += (size_t)BB*NF*ENC*2;        // 6.4 MB
    int*   flag    = (int*)  (ws + off); off += 256;
    unsigned* bar  = (unsigned*)(ws + off); off += 4096;
    if (ws_size < off) return;

    k_detect    <<<1, 256, 0, stream>>>(emb, flag, bar);
    k_prep_gates<<<2048, 256, 0, stream>>>(w_ih, w_hh, wcat, flag);
    k_prep_cvt8 <<<2048, 256, 0, stream>>>(fcn_w, fcnw_bf, (size_t)VCB*HD/8, flag);
    k_prep_cvt8 <<<128, 256, 0, stream>>>(W_w, Ww_bf, (size_t)ATTD*HD/8, flag);
    k_prep_cvt8 <<<1024, 256, 0, stream>>>(feat, feat_bf, (size_t)BB*NF*ENC/8, flag);
    k_mean      <<<BB, 256, 0, stream>>>(feat, mean_f, flag);
    k_init_hc   <<<64, 256, 0, stream>>>(mean_f, ihw, ihb, icw, icb, Hbuf, c_f32, flag);
    k_uhs       <<<dim3(98, 8), 256, 0, stream>>>(feat_bf, U_w, U_b, u_hs, flag);

    // whole 20-step decode loop in one cooperative launch (flag-wave sync)
    {
        void* kargs[18] = {
            (void*)&Hbuf, (void*)&c_f32, (void*)&Ww_bf, (void*)&W_b,
            (void*)&u_hs, (void*)&A_w, (void*)&A_b, (void*)&caps,
            (void*)&emb, (void*)&feat_bf, (void*)&lstm_in, (void*)&wcat,
            (void*)&b_ih, (void*)&b_hh, (void*)&Hall_bf, (void*)&d_out,
            (void*)&flag, (void*)&bar
        };
        hipLaunchCooperativeKernel((void*)k_decode, dim3(NBLK), dim3(DTPB),
                                   kargs, 0, stream);
    }

    k_fcn<<<477, 256, 0, stream>>>(Hall_bf, fcnw_bf, fcn_b, d_out, flag);
}

// Round 13
// 1451.378 us; speedup vs baseline: 1.0862x; 1.0862x over previous
//
#include <hip/hip_runtime.h>
#include <hip/hip_bf16.h>

// Problem constants (bert-base captioning decoder)
#define VCB 30522   // vocab
#define EMB 512     // embed size
#define ATTD 512    // attention dim
#define ENC 2048    // encoder dim
#define HD 512      // hidden dim
#define BB 32       // batch
#define NF 49       // image features
#define TSTEPS 20   // decode steps
#define EIN 2560    // EMB + ENC (lstm input)
#define KCAT 3072   // EIN + HD (fused gate GEMM K)
#define WSTRIDE 3080 // padded LDS row stride (bf16) -> row-to-row bank shift of 4
#define DTPB 512    // k_decode threads per block (8 waves)
#define NBLK 128    // k_decode blocks: each owns 4 hidden cols (16 wcat rows)

typedef __attribute__((ext_vector_type(8))) __bf16 bf16x8;
typedef __attribute__((ext_vector_type(4))) __bf16 bf16x4;
typedef __attribute__((ext_vector_type(4))) float floatx4;
typedef __hip_bfloat16 bf16;

__device__ __forceinline__ float bf2f(bf16 x){ return __bfloat162float(x); }
__device__ __forceinline__ bf16 f2bf(float x){ return __float2bfloat16(x); }
__device__ __forceinline__ float sigm(float x){ return 1.0f/(1.0f+expf(-x)); }
// fast tanh: (e^{2x}-1)/(e^{2x}+1) via hardware exp + rcp. |err| ~1e-6.
__device__ __forceinline__ float fast_tanh(float x){
    float e2 = __expf(2.0f*x);
    return 1.0f - 2.0f*__builtin_amdgcn_rcpf(e2 + 1.0f);
}

// ---- coherent (Infinity-Cache point) relaxed dword access -----------------
__device__ __forceinline__ unsigned coh_ld(const unsigned* p){
    return __hip_atomic_load(p, __ATOMIC_RELAXED, __HIP_MEMORY_SCOPE_AGENT);
}
__device__ __forceinline__ void coh_st(unsigned* p, unsigned v){
    __hip_atomic_store(p, v, __ATOMIC_RELAXED, __HIP_MEMORY_SCOPE_AGENT);
}
__device__ __forceinline__ unsigned pack2bf(float a, float b){
    unsigned short ua = __builtin_bit_cast(unsigned short, f2bf(a));
    unsigned short ub = __builtin_bit_cast(unsigned short, f2bf(b));
    return (unsigned)ua | ((unsigned)ub << 16);
}

// ---- one-way producer->consumer flags, two-tier burn-wait -----------------
// r0-vs-r10 accounting: launch-based (~2-5us kernel-boundary sync) and
// persistent flag-sync both land at ~50us/step => rendezvous is CHEAP; the
// PHASES (32-block attention, ~800KB/CU/step) were the cost. r11 spreads
// phase A over 4 thin stages x up-to-128 blocks, <=55KB per CU per stage.
// gpost: __syncthreads drains vmcnt(0) (sc1 stores AND loads ACKed at the
// coherent point) before tid0's relaxed add becomes visible.
// gwait: wave0 polls global flag (1 outstanding MALL load/block), publishes
// epoch to an LDS mirror polled by waves 1-7 (no fabric traffic).
__device__ __forceinline__ void gpost(unsigned* ctr){
    __syncthreads();
    if (threadIdx.x == 0)
        __hip_atomic_fetch_add(ctr, 1u, __ATOMIC_RELAXED, __HIP_MEMORY_SCOPE_AGENT);
}
__device__ __forceinline__ void gwait(const unsigned* ctr, unsigned tgt,
                                      volatile unsigned* sflag){
    float x = 1.0f;
    if (threadIdx.x < 64){
        while (coh_ld(ctr) < tgt){
#pragma unroll
            for (int i = 0; i < 8; ++i)
                x = __builtin_fmaf(x, 1.0000001f, 1e-12f);
        }
        if (threadIdx.x == 0) *sflag = tgt;       // LDS publish
    } else {
        while (*sflag < tgt){                     // LDS poll
#pragma unroll
            for (int i = 0; i < 32; ++i)
                x = __builtin_fmaf(x, 1.0000001f, 1e-12f);
        }
    }
    asm volatile("" :: "v"(x));
    __syncthreads();
}

// ---- dtype-adaptive load/store helpers (f=1: data is f32; f=0: bf16) ------
__device__ __forceinline__ float ld1(const void* base, size_t idx, int f){
    if (f) return ((const float*)base)[idx];
    return bf2f(((const bf16*)base)[idx]);
}
__device__ __forceinline__ bf16x8 ldbf8(const void* base, size_t idx, int f){
    if (f){
        const float* p = (const float*)base + idx;
        float4 a = *(const float4*)p, b = *(const float4*)(p+4);
        bf16x8 r;
        r[0]=(__bf16)a.x; r[1]=(__bf16)a.y; r[2]=(__bf16)a.z; r[3]=(__bf16)a.w;
        r[4]=(__bf16)b.x; r[5]=(__bf16)b.y; r[6]=(__bf16)b.z; r[7]=(__bf16)b.w;
        return r;
    }
    return *(const bf16x8*)((const bf16*)base + idx);
}
__device__ __forceinline__ bf16x8 bf8_of_f32(const float* p){
    float4 a = *(const float4*)p, b = *(const float4*)(p+4);
    bf16x8 r;
    r[0]=(__bf16)a.x; r[1]=(__bf16)a.y; r[2]=(__bf16)a.z; r[3]=(__bf16)a.w;
    r[4]=(__bf16)b.x; r[5]=(__bf16)b.y; r[6]=(__bf16)b.z; r[7]=(__bf16)b.w;
    return r;
}
__device__ __forceinline__ void st1(void* base, size_t idx, float v, int f){
    if (f) ((float*)base)[idx] = v;
    else   ((bf16*)base)[idx] = f2bf(v);
}

#define MFMA16(a,b,c) __builtin_amdgcn_mfma_f32_16x16x32_bf16(a,b,c,0,0,0)
// Verified fragment layout (learn_hip m89/m91):
//   A: lane holds A[m=lane&15][k=(lane>>4)*8+j]   (row-major [M][K])
//   B: lane holds Bt[n=lane&15][k=(lane>>4)*8+j]  (row-major [N][K])
//   D: lane holds D[row=(lane>>4)*4+r][col=lane&15]

// ---------------- kernel 0: dtype detect + flag zero -----------------------
__global__ void k_detect(const void* emb, int* flag, unsigned* bar){
    int tid = threadIdx.x;
    __shared__ int bad;
    if (tid == 0) bad = 0;
    for (int i = tid; i < 1024; i += 256) bar[i] = 0u;
    __syncthreads();
    const unsigned short* u = (const unsigned short*)emb;
    int local = 0;
    for (int i = tid; i < 4096; i += 256){
        int e = (u[i] >> 7) & 0xFF;
        if (e > 140) local = 1;           // |v| > 2^13: impossible for real data
    }
    if (local) bad = 1;
    __syncthreads();
    if (tid == 0) *flag = bad;
}

// ---------------- prep kernels: convert weights to bf16 once ---------------
// wcat[r][0..2559] = w_ih[r], wcat[r][2560..3071] = w_hh[r]   (r = gate*512+n)
__global__ void k_prep_gates(const void* w_ih, const void* w_hh, bf16* __restrict__ wcat,
                             const int* __restrict__ flag){
    int ff = *flag;
    int r = blockIdx.x, tid = threadIdx.x;
    for (int i = tid*8; i < KCAT; i += 2048){
        bf16x8 v;
        if (i + 8 <= EIN){
            v = ldbf8(w_ih, (size_t)r*EIN + i, ff);
        } else if (i >= EIN){
            v = ldbf8(w_hh, (size_t)r*HD + (i - EIN), ff);
        } else {
#pragma unroll
            for (int j = 0; j < 8; ++j){
                int k = i + j;
                v[j] = (__bf16)((k < EIN) ? ld1(w_ih, (size_t)r*EIN + k, ff)
                                          : ld1(w_hh, (size_t)r*HD + (k - EIN), ff));
            }
        }
        *(bf16x8*)(wcat + (size_t)r*KCAT + i) = v;
    }
}
// vectorized convert, n must be divisible by 8
__global__ void k_prep_cvt8(const void* src, bf16* __restrict__ dst, size_t n8,
                            const int* __restrict__ flag){
    int ff = *flag;
    size_t idx = (size_t)blockIdx.x*256 + threadIdx.x;
    size_t stride = (size_t)gridDim.x*256;
    for (size_t i = idx; i < n8; i += stride)
        *(bf16x8*)(dst + i*8) = ldbf8(src, i*8, ff);
}

// ---------------- kernel 1: mean over feature positions (f32 out) ----------
__global__ void k_mean(const void* feat, float* __restrict__ mean_f,
                       const int* __restrict__ flag){
    int ff = *flag;
    int b = blockIdx.x, tid = threadIdx.x;
    for (int i = 0; i < ENC/256; ++i){
        int e = i*256 + tid;
        size_t base = (size_t)b*NF*ENC + e;
        float s = 0.f;
        for (int n = 0; n < NF; ++n) s += ld1(feat, base + (size_t)n*ENC, ff);
        mean_f[b*ENC + e] = s * (1.0f/49.0f);
    }
}

// ---------------- kernel 2: h0/c0 = mean_f @ [ihw|icw]^T + b (MFMA) --------
__global__ void k_init_hc(const float* __restrict__ mean_f,
                          const void* ihw, const void* ihb,
                          const void* icw, const void* icb,
                          float* __restrict__ Hbuf, float* __restrict__ c_f32,
                          const int* __restrict__ flag){
    int ff = *flag;
    int tid = threadIdx.x, wave = tid>>6, lane = tid&63, quad = lane>>4, lq = lane&15;
    int n0 = blockIdx.x*16;
    int ng = n0 + lq;
    const void* w = (ng < HD) ? ihw : icw;
    size_t wrow = (size_t)(ng < HD ? ng : ng - HD)*ENC;
    floatx4 acc[2] = {{0,0,0,0},{0,0,0,0}};
    int kb = wave*512;
    for (int kk = 0; kk < 16; ++kk){
        int k = kb + kk*32 + quad*8;
        bf16x8 bfr = ldbf8(w, wrow + k, ff);
#pragma unroll
        for (int mt = 0; mt < 2; ++mt){
            bf16x8 afr = bf8_of_f32(mean_f + (size_t)(mt*16+lq)*ENC + k);
            acc[mt] = MFMA16(afr, bfr, acc[mt]);
        }
    }
    __shared__ float red[4][2][16][16];
#pragma unroll
    for (int mt = 0; mt < 2; ++mt)
        for (int r = 0; r < 4; ++r)
            red[wave][mt][quad*4+r][lq] = acc[mt][r];
    __syncthreads();
    for (int rep = 0; rep < 2; ++rep){
        int idx = rep*256 + tid;
        int mt = idx>>8, mm = (idx>>4)&15, nn = idx&15;
        float v = red[0][mt][mm][nn]+red[1][mt][mm][nn]+red[2][mt][mm][nn]+red[3][mt][mm][nn];
        int n_g = n0 + nn, b = mt*16 + mm;
        if (n_g < HD) Hbuf[b*HD + n_g]        = v + ld1(ihb, n_g, ff);
        else          c_f32[b*HD + (n_g-HD)]  = v + ld1(icb, n_g - HD, ff);
    }
}

// ---------------- kernel 3: u_hs = feat_bf @ U_w^T + U_b (MFMA, f32 out) ---
__global__ void k_uhs(const bf16* __restrict__ feat_bf, const void* U_w, const void* U_b,
                      float* __restrict__ u_hs, const int* __restrict__ flag){
    int ff = *flag;
    int tid = threadIdx.x, wave = tid>>6, lane = tid&63, quad = lane>>4, lq = lane&15;
    int m0 = blockIdx.x*16;
    int n0 = blockIdx.y*64 + wave*16;
    size_t arow = (size_t)(m0+lq)*ENC;
    size_t brow = (size_t)(n0+lq)*ENC;
    floatx4 acc = {0,0,0,0};
    for (int kk = 0; kk < ENC/32; ++kk){
        int k = kk*32 + quad*8;
        bf16x8 afr = *(const bf16x8*)(feat_bf + arow + k);
        bf16x8 bfr = ldbf8(U_w,  brow + k, ff);
        acc = MFMA16(afr, bfr, acc);
    }
    float ub = ld1(U_b, n0+lq, ff);
    for (int r = 0; r < 4; ++r){
        int m = m0 + quad*4 + r;
        u_hs[(size_t)m*ATTD + n0 + lq] = acc[r] + ub;
    }
}

// ---------------- kernel 4: persistent cooperative decode loop -------------
// Grid 128 x 512. Per step, 4 thin stages (r11: spread phase A):
//   A1 (bid<32):  w_ah GEMM [32x512]@[512x512]^T: block owns 16 cols, reads
//                 16KB Ww + 32KB h-frags (sc1) -> wah_u.      post flagW
//   A2 (bid<32):  scores+softmax for batch b=bid (u_hs 100KB) -> alpha_u,
//                 d_out alphas.                               post flagS
//   A3 (all 128): context e-slice (b=bid>>2, s=bid&3): 50KB feat -> ctx
//                 slice of lin_u; also emb piece.             post flagL
//   B  (all 128): gates MFMA (LDS wcat, 8-wave K-split) + LSTM pointwise
//                 -> h into lin_u h-section + Hall_bf.        post flagH
// Hazard audit: every producer's gpost drains its loads+stores (vmcnt(0)
// before the add); every reuse (wah_u, alpha_u, lin_u sections) is ordered
// transitively through the flag chain W->S->L->H. Monotonic counters.
__global__ void __launch_bounds__(DTPB) k_decode(
        float* __restrict__ Hbuf, const float* __restrict__ c0_f32,
        const bf16* __restrict__ Ww_bf, const void* __restrict__ W_b,
        const float* __restrict__ u_hs, const void* __restrict__ A_w,
        const void* __restrict__ A_b, const int* __restrict__ captions,
        const void* __restrict__ emb, const bf16* __restrict__ feat_bf,
        bf16* __restrict__ lstm_in, const bf16* __restrict__ wcat,
        const void* __restrict__ b_ih, const void* __restrict__ b_hh,
        bf16* __restrict__ Hall_bf, void* __restrict__ d_out,
        const int* __restrict__ flag, unsigned* __restrict__ bar,
        float* __restrict__ wah_u, float* __restrict__ alpha_u)
{
    const int ff = *flag;
    const int bid = blockIdx.x, tid = threadIdx.x;
    const int wave = tid>>6, lane = tid&63, quad = lane>>4, lq = lane&15;

    __shared__ bf16  wlds[16*WSTRIDE];  // 98.56 KB: this block's 16 wcat rows
    __shared__ float ubuf[4096];        // 16 KB: A-stage scratch UNION red[8]
    __shared__ float aw_s[ATTD];        // 2 KB (A2 blocks only)
    __shared__ float c_loc[BB*4];       // persistent c state (32 b x 4 cols)
    __shared__ float gbias[16];         // b_ih+b_hh for this block's 16 rows
    __shared__ unsigned sfW, sfS, sfL, sfH;

    unsigned* lin_u = (unsigned*)lstm_in;     // lstm_in as dwords (bf16 pairs)
    unsigned* flagW = bar;                    // w_ah done      (+32/step)
    unsigned* flagS = bar + 64;               // alphas done    (+32/step)
    unsigned* flagL = bar + 128;              // lstm_in done   (+128/step)
    unsigned* flagH = bar + 192;              // h published    (+128, prologue too)
    unsigned* wahu_u  = (unsigned*)wah_u;
    unsigned* alphu_u = (unsigned*)alpha_u;

    if (tid == 0){ sfW = 0u; sfS = 0u; sfL = 0u; sfH = 0u; }

    // ---- prologue: load persistent state ----
    for (int n = 0; n < 16; ++n){
        int g = n>>2, j = n&3;
        const bf16* src = wcat + (size_t)(g*HD + (bid<<2) + j)*KCAT;
        for (int c8 = tid; c8 < KCAT/8; c8 += DTPB)
            *(bf16x8*)(wlds + n*WSTRIDE + c8*8) = *(const bf16x8*)(src + c8*8);
    }
    if (tid < 128){
        int bb = tid&31, j = tid>>5, col = (bid<<2)+j;
        c_loc[bb*4+j] = c0_f32[bb*HD + col];   // plain: pre-kernel data
    }
    if (tid < 64){
        // h-section of lstm_in for t=0 (h0 from Hbuf slot 0), dword-packed
        int bb = tid&31, j2 = tid>>5;
        int c0 = (bid<<2) + 2*j2;
        float h0 = Hbuf[bb*HD + c0], h1 = Hbuf[bb*HD + c0 + 1];
        coh_st(lin_u + (size_t)bb*(KCAT/2) + (EIN + c0)/2, pack2bf(h0, h1));
    }
    if (tid < 16){
        int g = tid>>2, j = tid&3, col = (bid<<2)+j;
        gbias[tid] = ld1(b_ih, g*HD+col, ff) + ld1(b_hh, g*HD+col, ff);
    }
    if (bid < BB)
        for (int i = tid; i < ATTD; i += DTPB) aw_s[i] = ld1(A_w, i, ff);
    gpost(flagH);                       // publish #0 (h0 section written)

    // ubuf views (sequential reuse, ordered by gwait/gpost __syncthreads)
    float* wah_s   = ubuf + 512;    // [512]  A2
    float* sc_s    = ubuf + 1024;   // [52]   A2
    float* alpha_s = ubuf + 1088;   // [52]   A3
    float (*red)[2][16][16] = (float (*)[2][16][16])ubuf;  // [8][2][16][16]

    for (int t = 0; t < TSTEPS; ++t){
        if (bid < BB){
            // ===== A1: w_ah cols [16*bid .. +16) for all 32 batches =====
            gwait(flagH, 128u*(unsigned)(t+1), &sfH);
            {
                int n0 = bid<<4;
                int kb = wave*64;               // K split 8x64
                floatx4 acc0 = {0,0,0,0}, acc1 = {0,0,0,0};
                const bf16* brow = Ww_bf + (size_t)(n0+lq)*HD;
                union U8 { unsigned u[4]; bf16x8 v; };
#pragma unroll
                for (int kk = 0; kk < 2; ++kk){
                    int k = kb + kk*32 + quad*8;
                    bf16x8 bfr = *(const bf16x8*)(brow + k);
                    U8 a0, a1;
                    const unsigned* ar0 = lin_u + (size_t)lq*(KCAT/2) + (EIN+k)/2;
                    const unsigned* ar1 = lin_u + (size_t)(16+lq)*(KCAT/2) + (EIN+k)/2;
#pragma unroll
                    for (int q = 0; q < 4; ++q){
                        a0.u[q] = coh_ld(ar0 + q);
                        a1.u[q] = coh_ld(ar1 + q);
                    }
                    acc0 = MFMA16(a0.v, bfr, acc0);
                    acc1 = MFMA16(a1.v, bfr, acc1);
                }
#pragma unroll
                for (int r = 0; r < 4; ++r){
                    red[wave][0][quad*4+r][lq] = acc0[r];
                    red[wave][1][quad*4+r][lq] = acc1[r];
                }
            }
            __syncthreads();
            {
                int b = tid>>4, c = tid&15;
                int mt = b>>4, mm = b&15;
                float s = 0.f;
#pragma unroll
                for (int w8 = 0; w8 < 8; ++w8) s += red[w8][mt][mm][c];
                int col = (bid<<4) + c;
                coh_st(wahu_u + (size_t)b*ATTD + col,
                       __float_as_uint(s + ld1(W_b, col, ff)));
            }
            gpost(flagW);

            // ===== A2: scores + softmax + alphas (batch b = bid) =====
            gwait(flagW, 32u*(unsigned)(t+1), &sfW);
            const int b = bid;
            wah_s[tid] = __uint_as_float(coh_ld(wahu_u + (size_t)b*ATTD + tid));
            __syncthreads();
            {
                int a0 = lane*8;
                for (int n = wave; n < NF; n += 8){
                    const float* up = u_hs + (size_t)(b*NF + n)*ATTD + a0;
                    float4 u0 = *(const float4*)up;
                    float4 u1 = *(const float4*)(up + 4);
                    float p0 = fast_tanh(u0.x + wah_s[a0+0])*aw_s[a0+0]
                             + fast_tanh(u0.y + wah_s[a0+1])*aw_s[a0+1]
                             + fast_tanh(u0.z + wah_s[a0+2])*aw_s[a0+2]
                             + fast_tanh(u0.w + wah_s[a0+3])*aw_s[a0+3];
                    float p1 = fast_tanh(u1.x + wah_s[a0+4])*aw_s[a0+4]
                             + fast_tanh(u1.y + wah_s[a0+5])*aw_s[a0+5]
                             + fast_tanh(u1.z + wah_s[a0+6])*aw_s[a0+6]
                             + fast_tanh(u1.w + wah_s[a0+7])*aw_s[a0+7];
                    float p = p0 + p1;
                    for (int off = 32; off; off >>= 1) p += __shfl_down(p, off);
                    if (lane == 0) sc_s[n] = p + ld1(A_b, 0, ff);
                }
            }
            __syncthreads();
            if (wave == 0){
                float v = (lane < NF) ? sc_s[lane] : -1e30f;
                float mx = v;
                for (int off = 32; off; off >>= 1) mx = fmaxf(mx, __shfl_down(mx, off));
                mx = __shfl(mx, 0);
                float e = (lane < NF) ? expf(v - mx) : 0.f;
                float s = e;
                for (int off = 32; off; off >>= 1) s += __shfl_down(s, off);
                s = __shfl(s, 0);
                if (lane < NF){
                    float al = e / s;
                    coh_st(alphu_u + b*64 + lane, __float_as_uint(al));
                    st1(d_out, (size_t)BB*TSTEPS*VCB + (size_t)b*(TSTEPS*NF) + t*NF + lane, al, ff);
                }
            }
            gpost(flagS);
        }
        // ===== A3: context e-slice + emb piece (b=bid>>2, s=bid&3) =====
        gwait(flagS, 32u*(unsigned)(t+1), &sfS);
        {
            const int b = bid>>2, sl = bid&3;
            if (tid < NF) alpha_s[tid] = __uint_as_float(coh_ld(alphu_u + b*64 + tid));
            __syncthreads();
            if (tid < 256){
                int col = sl*512 + 2*tid;
                const bf16* fb = feat_bf + (size_t)b*NF*ENC + col;
                float a0 = 0.f, a1 = 0.f;
#pragma unroll 7
                for (int n = 0; n < NF; ++n){
                    unsigned fv = *(const unsigned*)(fb + (size_t)n*ENC);
                    float lo = __uint_as_float(fv << 16);
                    float hi = __uint_as_float(fv & 0xffff0000u);
                    float al = alpha_s[n];
                    a0 += al*lo; a1 += al*hi;
                }
                coh_st(lin_u + (size_t)b*(KCAT/2) + (EMB+col)/2, pack2bf(a0, a1));
            } else if (tid >= 448){
                int cap = captions[b*21 + t];
                int col = sl*128 + 2*(tid - 448);
                coh_st(lin_u + (size_t)b*(KCAT/2) + col/2,
                       pack2bf(ld1(emb, (size_t)cap*EMB + col,     ff),
                               ld1(emb, (size_t)cap*EMB + col + 1, ff)));
            }
            gpost(flagL);
        }
        gwait(flagL, 128u*(unsigned)(t+1), &sfL);

        // ===== B: gates MFMA (LDS wcat, 8-wave K-split) + LSTM pointwise ===
        {
            int kb = wave*384;                      // K split 8x384 over waves
            floatx4 acc0 = {0,0,0,0}, acc1 = {0,0,0,0};
            const bf16* wrow = wlds + (size_t)lq*WSTRIDE;  // 16 distinct B-rows
            const unsigned* ar0 = lin_u + (size_t)lq*(KCAT/2);
            const unsigned* ar1 = lin_u + (size_t)(16+lq)*(KCAT/2);
            union U8 { unsigned u[4]; bf16x8 v; };
#pragma unroll
            for (int kk = 0; kk < 12; ++kk){
                int kd = (kb + kk*32 + quad*8) >> 1;   // dword index
                bf16x8 bfr = *(const bf16x8*)(wrow + kb + kk*32 + quad*8);
                U8 a0, a1;
#pragma unroll
                for (int q = 0; q < 4; ++q){
                    a0.u[q] = coh_ld(ar0 + kd + q);
                    a1.u[q] = coh_ld(ar1 + kd + q);
                }
                acc0 = MFMA16(a0.v, bfr, acc0);
                acc1 = MFMA16(a1.v, bfr, acc1);
            }
#pragma unroll
            for (int r = 0; r < 4; ++r){
                red[wave][0][quad*4+r][lq] = acc0[r];
                red[wave][1][quad*4+r][lq] = acc1[r];
            }
        }
        __syncthreads();
        if (tid < 64){
            int bb = tid&31, j2 = tid>>5;           // j2: col pair 0/1
            int mt = bb>>4, mm = bb&15;
            float hn[2];
#pragma unroll
            for (int sub = 0; sub < 2; ++sub){
                int j = 2*j2 + sub;                 // col-in-block 0..3
                float G[4];
#pragma unroll
                for (int g = 0; g < 4; ++g){
                    int n = g*4 + j;                // B-row n = gate*4 + col
                    float s = 0.f;
#pragma unroll
                    for (int w8 = 0; w8 < 8; ++w8) s += red[w8][mt][mm][n];
                    G[g] = s + gbias[n];
                }
                float c_old = c_loc[bb*4+j];
                float c_new = sigm(G[1])*c_old + sigm(G[0])*tanhf(G[2]);
                float h_new = sigm(G[3])*tanhf(c_new);
                c_loc[bb*4+j] = c_new;
                hn[sub] = h_new;
            }
            int colb = (bid<<2) + 2*j2;
            ((unsigned*)Hall_bf)[((size_t)t*BB*HD + bb*HD + colb) >> 1] = pack2bf(hn[0], hn[1]);
            coh_st(lin_u + (size_t)bb*(KCAT/2) + (EIN + colb)/2, pack2bf(hn[0], hn[1]));
        }
        gpost(flagH);                   // h(t+1) published (+ B(t) reads done)
    }
}

// ---------------- kernel 6: preds = Hall_bf @ fcnw_bf^T + fcn_b ------------
__global__ void __launch_bounds__(256) k_fcn(const bf16* __restrict__ Hall_bf,
                                             const bf16* __restrict__ fcnw_bf,
                                             const void* fcn_b, void* d_out,
                                             const int* __restrict__ flag){
    int ff = *flag;
    int tid = threadIdx.x, wave = tid>>6, lane = tid&63, quad = lane>>4, lq = lane&15;
    int n0 = blockIdx.x*64 + wave*16;
    int v = n0 + lq;
    int vc = (v < VCB) ? v : (VCB-1);
    const bf16* brow = fcnw_bf + (size_t)vc*HD;
    bf16x8 bfr[16];
#pragma unroll
    for (int kk = 0; kk < 16; ++kk) bfr[kk] = *(const bf16x8*)(brow + kk*32 + quad*8);
    float bias = ld1(fcn_b, vc, ff);
    for (int mt = 0; mt < 40; ++mt){
        const bf16* arow = Hall_bf + (size_t)(mt*16 + lq)*HD;
        floatx4 acc = {0,0,0,0};
#pragma unroll
        for (int kk = 0; kk < 16; ++kk){
            bf16x8 afr = *(const bf16x8*)(arow + kk*32 + quad*8);
            acc = MFMA16(afr, bfr[kk], acc);
        }
        if (v < VCB){
#pragma unroll
            for (int r = 0; r < 4; ++r){
                int m = mt*16 + quad*4 + r;
                int b = m & 31, tt = m >> 5;
                st1(d_out, (size_t)b*(TSTEPS*VCB) + (size_t)tt*VCB + v, acc[r] + bias, ff);
            }
        }
    }
}

// ---------------- host launch ---------------------------------------------
extern "C" void kernel_launch(void* const* d_in, const int* in_sizes, int n_in,
                              void* d_out, int out_size, void* d_ws, size_t ws_size,
                              hipStream_t stream) {
    const void* feat  = d_in[0];
    const int*  caps  = (const int*)d_in[1];
    const void* emb   = d_in[2];
    const void* W_w   = d_in[3];
    const void* W_b   = d_in[4];
    const void* U_w   = d_in[5];
    const void* U_b   = d_in[6];
    const void* A_w   = d_in[7];
    const void* A_b   = d_in[8];
    const void* ihw   = d_in[9];
    const void* ihb   = d_in[10];
    const void* icw   = d_in[11];
    const void* icb   = d_in[12];
    const void* w_ih  = d_in[13];
    const void* w_hh  = d_in[14];
    const void* b_ih  = d_in[15];
    const void* b_hh  = d_in[16];
    const void* fcn_w = d_in[17];
    const void* fcn_b = d_in[18];

    // workspace layout (16B-aligned)
    char* ws = (char*)d_ws;
    size_t off = 0;
    float* u_hs    = (float*)(ws + off); off += (size_t)BB*NF*ATTD*4;       // 3.2 MB
    float* c_f32   = (float*)(ws + off); off += (size_t)BB*HD*4;            // 64 KB
    float* mean_f  = (float*)(ws + off); off += (size_t)BB*ENC*4;           // 256 KB
    float* Hbuf    = (float*)(ws + off); off += (size_t)(TSTEPS+1)*BB*HD*4; // 1.38 MB
    bf16*  lstm_in = (bf16*) (ws + off); off += (size_t)BB*KCAT*2;          // 192 KB
    bf16*  Hall_bf = (bf16*) (ws + off); off += (size_t)TSTEPS*BB*HD*2;     // 640 KB
    bf16*  wcat    = (bf16*) (ws + off); off += (size_t)4*HD*KCAT*2;        // 12.6 MB
    bf16*  fcnw_bf = (bf16*) (ws + off); off += (size_t)VCB*HD*2;           // 31.25 MB
    bf16*  Ww_bf   = (bf16*) (ws + off); off += (size_t)ATTD*HD*2;          // 512 KB
    bf16*  feat_bf = (bf16*) (ws + off); off += (size_t)BB*NF*ENC*2;        // 6.4 MB
    float* wah_u   = (float*)(ws + off); off += (size_t)BB*ATTD*4;          // 64 KB
    float* alpha_u = (float*)(ws + off); off += (size_t)BB*64*4;            // 8 KB
    int*   flag    = (int*)  (ws + off); off += 256;
    unsigned* bar  = (unsigned*)(ws + off); off += 4096;
    if (ws_size < off) return;

    k_detect    <<<1, 256, 0, stream>>>(emb, flag, bar);
    k_prep_gates<<<2048, 256, 0, stream>>>(w_ih, w_hh, wcat, flag);
    k_prep_cvt8 <<<2048, 256, 0, stream>>>(fcn_w, fcnw_bf, (size_t)VCB*HD/8, flag);
    k_prep_cvt8 <<<128, 256, 0, stream>>>(W_w, Ww_bf, (size_t)ATTD*HD/8, flag);
    k_prep_cvt8 <<<1024, 256, 0, stream>>>(feat, feat_bf, (size_t)BB*NF*ENC/8, flag);
    k_mean      <<<BB, 256, 0, stream>>>(feat, mean_f, flag);
    k_init_hc   <<<64, 256, 0, stream>>>(mean_f, ihw, ihb, icw, icb, Hbuf, c_f32, flag);
    k_uhs       <<<dim3(98, 8), 256, 0, stream>>>(feat_bf, U_w, U_b, u_hs, flag);

    // whole 20-step decode loop in one cooperative launch (4-stage pipeline)
    {
        void* kargs[20] = {
            (void*)&Hbuf, (void*)&c_f32, (void*)&Ww_bf, (void*)&W_b,
            (void*)&u_hs, (void*)&A_w, (void*)&A_b, (void*)&caps,
            (void*)&emb, (void*)&feat_bf, (void*)&lstm_in, (void*)&wcat,
            (void*)&b_ih, (void*)&b_hh, (void*)&Hall_bf, (void*)&d_out,
            (void*)&flag, (void*)&bar, (void*)&wah_u, (void*)&alpha_u
        };
        hipLaunchCooperativeKernel((void*)k_decode, dim3(NBLK), dim3(DTPB),
                                   kargs, 0, stream);
    }

    k_fcn<<<477, 256, 0, stream>>>(Hall_bf, fcnw_bf, fcn_b, d_out, flag);
}

// Round 14
// 1422.445 us; speedup vs baseline: 1.1083x; 1.0203x over previous
//
#include <hip/hip_runtime.h>
#include <hip/hip_bf16.h>

// Problem constants (bert-base captioning decoder)
#define VCB 30522   // vocab
#define EMB 512     // embed size
#define ATTD 512    // attention dim
#define ENC 2048    // encoder dim
#define HD 512      // hidden dim
#define BB 32       // batch
#define NF 49       // image features
#define TSTEPS 20   // decode steps
#define EIN 2560    // EMB + ENC (lstm input)
#define KCAT 3072   // EIN + HD (fused gate GEMM K)
#define WSTRIDE 3080 // padded LDS row stride (bf16) -> row-to-row bank shift of 4
#define DTPB 512    // k_decode threads per block (8 waves)
#define NBLK 128    // k_decode blocks: each owns 4 hidden cols (16 wcat rows)

typedef __attribute__((ext_vector_type(8))) __bf16 bf16x8;
typedef __attribute__((ext_vector_type(4))) __bf16 bf16x4;
typedef __attribute__((ext_vector_type(4))) float floatx4;
typedef __hip_bfloat16 bf16;

__device__ __forceinline__ float bf2f(bf16 x){ return __bfloat162float(x); }
__device__ __forceinline__ bf16 f2bf(float x){ return __float2bfloat16(x); }
__device__ __forceinline__ float sigm(float x){ return 1.0f/(1.0f+expf(-x)); }
// fast tanh: (e^{2x}-1)/(e^{2x}+1) via hardware exp + rcp. |err| ~1e-6.
__device__ __forceinline__ float fast_tanh(float x){
    float e2 = __expf(2.0f*x);
    return 1.0f - 2.0f*__builtin_amdgcn_rcpf(e2 + 1.0f);
}

// ---- coherent (Infinity-Cache point) relaxed dword access -----------------
__device__ __forceinline__ unsigned coh_ld(const unsigned* p){
    return __hip_atomic_load(p, __ATOMIC_RELAXED, __HIP_MEMORY_SCOPE_AGENT);
}
__device__ __forceinline__ void coh_st(unsigned* p, unsigned v){
    __hip_atomic_store(p, v, __ATOMIC_RELAXED, __HIP_MEMORY_SCOPE_AGENT);
}
__device__ __forceinline__ unsigned pack2bf(float a, float b){
    unsigned short ua = __builtin_bit_cast(unsigned short, f2bf(a));
    unsigned short ub = __builtin_bit_cast(unsigned short, f2bf(b));
    return (unsigned)ua | ((unsigned)ub << 16);
}

// ---- slot-based producer->consumer sync (r14) -----------------------------
// r10/r13 accounting: rendezvous ~= 10us each regardless of protocol -- all
// prior protocols funneled 32-128 atomic RMWs through ONE MALL line, which
// SERIALIZE at the coherence point (~100-150ns each at idle clocks). r14:
// arrival = one relaxed STORE per block into its OWN slot (distinct
// addresses pipeline freely); detection = wave-parallel poll (64 lanes load
// 64-128 slots, __all test), LDS mirror for waves 1-7.
// Visibility: gpost_slot's __syncthreads drains vmcnt(0) (all data sc1
// stores ACKed at MALL) before the slot store issues -> consumer seeing
// slot>=ep implies data visible.
__device__ __forceinline__ void gpost_slot(unsigned* slot, unsigned ep){
    __syncthreads();
    if (threadIdx.x == 0) coh_st(slot, ep);
}
// two=1: 128 producers (slots[0..127]); two=0: 32 producers (slots[0..31],
// slot array padded to 64 so lane loads stay in-bounds).
__device__ __forceinline__ void gwaitN(const unsigned* slots, int two, unsigned tgt,
                                       volatile unsigned* sflag){
    float x = 1.0f;
    if (threadIdx.x < 64){
        int l = threadIdx.x;
        for (;;){
            unsigned a = coh_ld(slots + l);
            bool ok;
            if (two){
                unsigned b = coh_ld(slots + 64 + l);
                ok = (a >= tgt) && (b >= tgt);
            } else {
                ok = (l < 32) ? (a >= tgt) : true;
            }
            if (__all(ok)) break;
#pragma unroll
            for (int i = 0; i < 8; ++i)
                x = __builtin_fmaf(x, 1.0000001f, 1e-12f);
        }
        if (l == 0) *sflag = tgt;
    } else {
        while (*sflag < tgt){
#pragma unroll
            for (int i = 0; i < 32; ++i)
                x = __builtin_fmaf(x, 1.0000001f, 1e-12f);
        }
    }
    asm volatile("" :: "v"(x));
    __syncthreads();
}

// ---- dtype-adaptive load/store helpers (f=1: data is f32; f=0: bf16) ------
__device__ __forceinline__ float ld1(const void* base, size_t idx, int f){
    if (f) return ((const float*)base)[idx];
    return bf2f(((const bf16*)base)[idx]);
}
__device__ __forceinline__ bf16x8 ldbf8(const void* base, size_t idx, int f){
    if (f){
        const float* p = (const float*)base + idx;
        float4 a = *(const float4*)p, b = *(const float4*)(p+4);
        bf16x8 r;
        r[0]=(__bf16)a.x; r[1]=(__bf16)a.y; r[2]=(__bf16)a.z; r[3]=(__bf16)a.w;
        r[4]=(__bf16)b.x; r[5]=(__bf16)b.y; r[6]=(__bf16)b.z; r[7]=(__bf16)b.w;
        return r;
    }
    return *(const bf16x8*)((const bf16*)base + idx);
}
__device__ __forceinline__ bf16x8 bf8_of_f32(const float* p){
    float4 a = *(const float4*)p, b = *(const float4*)(p+4);
    bf16x8 r;
    r[0]=(__bf16)a.x; r[1]=(__bf16)a.y; r[2]=(__bf16)a.z; r[3]=(__bf16)a.w;
    r[4]=(__bf16)b.x; r[5]=(__bf16)b.y; r[6]=(__bf16)b.z; r[7]=(__bf16)b.w;
    return r;
}
__device__ __forceinline__ void st1(void* base, size_t idx, float v, int f){
    if (f) ((float*)base)[idx] = v;
    else   ((bf16*)base)[idx] = f2bf(v);
}

#define MFMA16(a,b,c) __builtin_amdgcn_mfma_f32_16x16x32_bf16(a,b,c,0,0,0)
// Verified fragment layout (learn_hip m89/m91):
//   A: lane holds A[m=lane&15][k=(lane>>4)*8+j]   (row-major [M][K])
//   B: lane holds Bt[n=lane&15][k=(lane>>4)*8+j]  (row-major [N][K])
//   D: lane holds D[row=(lane>>4)*4+r][col=lane&15]

// ---------------- kernel 0: dtype detect + slot zero -----------------------
__global__ void k_detect(const void* emb, int* flag, unsigned* bar){
    int tid = threadIdx.x;
    __shared__ int bad;
    if (tid == 0) bad = 0;
    for (int i = tid; i < 1024; i += 256) bar[i] = 0u;
    __syncthreads();
    const unsigned short* u = (const unsigned short*)emb;
    int local = 0;
    for (int i = tid; i < 4096; i += 256){
        int e = (u[i] >> 7) & 0xFF;
        if (e > 140) local = 1;           // |v| > 2^13: impossible for real data
    }
    if (local) bad = 1;
    __syncthreads();
    if (tid == 0) *flag = bad;
}

// ---------------- prep kernels: convert weights to bf16 once ---------------
// wcat[r][0..2559] = w_ih[r], wcat[r][2560..3071] = w_hh[r]   (r = gate*512+n)
__global__ void k_prep_gates(const void* w_ih, const void* w_hh, bf16* __restrict__ wcat,
                             const int* __restrict__ flag){
    int ff = *flag;
    int r = blockIdx.x, tid = threadIdx.x;
    for (int i = tid*8; i < KCAT; i += 2048){
        bf16x8 v;
        if (i + 8 <= EIN){
            v = ldbf8(w_ih, (size_t)r*EIN + i, ff);
        } else if (i >= EIN){
            v = ldbf8(w_hh, (size_t)r*HD + (i - EIN), ff);
        } else {
#pragma unroll
            for (int j = 0; j < 8; ++j){
                int k = i + j;
                v[j] = (__bf16)((k < EIN) ? ld1(w_ih, (size_t)r*EIN + k, ff)
                                          : ld1(w_hh, (size_t)r*HD + (k - EIN), ff));
            }
        }
        *(bf16x8*)(wcat + (size_t)r*KCAT + i) = v;
    }
}
// vectorized convert, n must be divisible by 8
__global__ void k_prep_cvt8(const void* src, bf16* __restrict__ dst, size_t n8,
                            const int* __restrict__ flag){
    int ff = *flag;
    size_t idx = (size_t)blockIdx.x*256 + threadIdx.x;
    size_t stride = (size_t)gridDim.x*256;
    for (size_t i = idx; i < n8; i += stride)
        *(bf16x8*)(dst + i*8) = ldbf8(src, i*8, ff);
}

// ---------------- kernel 1: mean over feature positions (f32 out) ----------
__global__ void k_mean(const void* feat, float* __restrict__ mean_f,
                       const int* __restrict__ flag){
    int ff = *flag;
    int b = blockIdx.x, tid = threadIdx.x;
    for (int i = 0; i < ENC/256; ++i){
        int e = i*256 + tid;
        size_t base = (size_t)b*NF*ENC + e;
        float s = 0.f;
        for (int n = 0; n < NF; ++n) s += ld1(feat, base + (size_t)n*ENC, ff);
        mean_f[b*ENC + e] = s * (1.0f/49.0f);
    }
}

// ---------------- kernel 2: h0/c0 = mean_f @ [ihw|icw]^T + b (MFMA) --------
__global__ void k_init_hc(const float* __restrict__ mean_f,
                          const void* ihw, const void* ihb,
                          const void* icw, const void* icb,
                          float* __restrict__ Hbuf, float* __restrict__ c_f32,
                          const int* __restrict__ flag){
    int ff = *flag;
    int tid = threadIdx.x, wave = tid>>6, lane = tid&63, quad = lane>>4, lq = lane&15;
    int n0 = blockIdx.x*16;
    int ng = n0 + lq;
    const void* w = (ng < HD) ? ihw : icw;
    size_t wrow = (size_t)(ng < HD ? ng : ng - HD)*ENC;
    floatx4 acc[2] = {{0,0,0,0},{0,0,0,0}};
    int kb = wave*512;
    for (int kk = 0; kk < 16; ++kk){
        int k = kb + kk*32 + quad*8;
        bf16x8 bfr = ldbf8(w, wrow + k, ff);
#pragma unroll
        for (int mt = 0; mt < 2; ++mt){
            bf16x8 afr = bf8_of_f32(mean_f + (size_t)(mt*16+lq)*ENC + k);
            acc[mt] = MFMA16(afr, bfr, acc[mt]);
        }
    }
    __shared__ float red[4][2][16][16];
#pragma unroll
    for (int mt = 0; mt < 2; ++mt)
        for (int r = 0; r < 4; ++r)
            red[wave][mt][quad*4+r][lq] = acc[mt][r];
    __syncthreads();
    for (int rep = 0; rep < 2; ++rep){
        int idx = rep*256 + tid;
        int mt = idx>>8, mm = (idx>>4)&15, nn = idx&15;
        float v = red[0][mt][mm][nn]+red[1][mt][mm][nn]+red[2][mt][mm][nn]+red[3][mt][mm][nn];
        int n_g = n0 + nn, b = mt*16 + mm;
        if (n_g < HD) Hbuf[b*HD + n_g]        = v + ld1(ihb, n_g, ff);
        else          c_f32[b*HD + (n_g-HD)]  = v + ld1(icb, n_g - HD, ff);
    }
}

// ---------------- kernel 3: u_hs = feat_bf @ U_w^T + U_b (MFMA, f32 out) ---
__global__ void k_uhs(const bf16* __restrict__ feat_bf, const void* U_w, const void* U_b,
                      float* __restrict__ u_hs, const int* __restrict__ flag){
    int ff = *flag;
    int tid = threadIdx.x, wave = tid>>6, lane = tid&63, quad = lane>>4, lq = lane&15;
    int m0 = blockIdx.x*16;
    int n0 = blockIdx.y*64 + wave*16;
    size_t arow = (size_t)(m0+lq)*ENC;
    size_t brow = (size_t)(n0+lq)*ENC;
    floatx4 acc = {0,0,0,0};
    for (int kk = 0; kk < ENC/32; ++kk){
        int k = kk*32 + quad*8;
        bf16x8 afr = *(const bf16x8*)(feat_bf + arow + k);
        bf16x8 bfr = ldbf8(U_w,  brow + k, ff);
        acc = MFMA16(afr, bfr, acc);
    }
    float ub = ld1(U_b, n0+lq, ff);
    for (int r = 0; r < 4; ++r){
        int m = m0 + quad*4 + r;
        u_hs[(size_t)m*ATTD + n0 + lq] = acc[r] + ub;
    }
}

// ---------------- kernel 4: persistent cooperative decode loop -------------
// Grid 128 x 512. Per step, 3 stages, slot-synced (sH -> A1 -> sW -> A23 ->
// sL -> B -> sH):
//   A1 (bid<32):   w_ah GEMM: block owns 16 cols x 32 batches (16KB Ww,
//                  h-frags via sc1) -> wah_u.                 slot sW[bid]
//   A23 (all 128): b=bid>>2, sl=bid&3: scores+softmax for batch b
//                  (4x redundant, u_hs L2-hot) -> alphas in LDS; ctx
//                  e-slice (50KB feat) + emb piece -> lin_u.  slot sL[bid]
//                  d_out alphas written by sl==0 only.
//   B  (all 128):  gates MFMA (LDS wcat, 8-wave K-split) + LSTM pointwise
//                  -> h into lin_u h-section + Hall_bf.       slot sH[bid]
// Hazard audit (transitive through slot chain, monotone epochs):
//   A1(t) overwrites wah_u read by A23(t-1): gated sH(t)<-B(t-1)<-sL(t-1)
//     <-A23(t-1) post (drained). A23(t) overwrites lin_u ctx read by B(t-1):
//     gated sW(t)<-A1(t)<-sH(t)<-B(t-1) post (drained). B(t) overwrites
//     lin_u h read by A1(t): gated sL(t)<-A23(t)<-sW(t)<-A1(t) post. All ok.
__global__ void __launch_bounds__(DTPB) k_decode(
        float* __restrict__ Hbuf, const float* __restrict__ c0_f32,
        const bf16* __restrict__ Ww_bf, const void* __restrict__ W_b,
        const float* __restrict__ u_hs, const void* __restrict__ A_w,
        const void* __restrict__ A_b, const int* __restrict__ captions,
        const void* __restrict__ emb, const bf16* __restrict__ feat_bf,
        bf16* __restrict__ lstm_in, const bf16* __restrict__ wcat,
        const void* __restrict__ b_ih, const void* __restrict__ b_hh,
        bf16* __restrict__ Hall_bf, void* __restrict__ d_out,
        const int* __restrict__ flag, unsigned* __restrict__ bar,
        float* __restrict__ wah_u)
{
    const int ff = *flag;
    const int bid = blockIdx.x, tid = threadIdx.x;
    const int wave = tid>>6, lane = tid&63, quad = lane>>4, lq = lane&15;

    __shared__ bf16  wlds[16*WSTRIDE];  // 98.56 KB: this block's 16 wcat rows
    __shared__ float ubuf[4096];        // 16 KB: stage scratch UNION red[8]
    __shared__ float aw_s[ATTD];        // 2 KB: A_w (all blocks run A23)
    __shared__ float c_loc[BB*4];       // persistent c state (32 b x 4 cols)
    __shared__ float gbias[16];         // b_ih+b_hh for this block's 16 rows
    __shared__ unsigned sfW, sfL, sfH;  // LDS epoch mirrors

    unsigned* lin_u = (unsigned*)lstm_in;     // lstm_in as dwords (bf16 pairs)
    unsigned* sH = bar;                       // 128 slots: h published
    unsigned* sW = bar + 128;                 // 32 slots (padded to 64): w_ah done
    unsigned* sL = bar + 256;                 // 128 slots: lstm_in done
    unsigned* wahu_u = (unsigned*)wah_u;

    if (tid == 0){ sfW = 0u; sfL = 0u; sfH = 0u; }

    // ---- prologue: load persistent state ----
    for (int n = 0; n < 16; ++n){
        int g = n>>2, j = n&3;
        const bf16* src = wcat + (size_t)(g*HD + (bid<<2) + j)*KCAT;
        for (int c8 = tid; c8 < KCAT/8; c8 += DTPB)
            *(bf16x8*)(wlds + n*WSTRIDE + c8*8) = *(const bf16x8*)(src + c8*8);
    }
    if (tid < 128){
        int bb = tid&31, j = tid>>5, col = (bid<<2)+j;
        c_loc[bb*4+j] = c0_f32[bb*HD + col];   // plain: pre-kernel data
    }
    if (tid < 64){
        // h-section of lstm_in for t=0 (h0 from Hbuf slot 0), dword-packed
        int bb = tid&31, j2 = tid>>5;
        int c0 = (bid<<2) + 2*j2;
        float h0 = Hbuf[bb*HD + c0], h1 = Hbuf[bb*HD + c0 + 1];
        coh_st(lin_u + (size_t)bb*(KCAT/2) + (EIN + c0)/2, pack2bf(h0, h1));
    }
    if (tid < 16){
        int g = tid>>2, j = tid&3, col = (bid<<2)+j;
        gbias[tid] = ld1(b_ih, g*HD+col, ff) + ld1(b_hh, g*HD+col, ff);
    }
    for (int i = tid; i < ATTD; i += DTPB) aw_s[i] = ld1(A_w, i, ff);
    gpost_slot(sH + bid, 1u);           // publish #1 (h0 section written)

    // ubuf views (sequential reuse, ordered by slot-sync __syncthreads)
    float* wah_s   = ubuf + 512;    // [512]  A23
    float* sc_s    = ubuf + 1024;   // [52]   A23
    float* alpha_s = ubuf + 1088;   // [52]   A23
    float (*red)[2][16][16] = (float (*)[2][16][16])ubuf;  // [8][2][16][16]

    for (int t = 0; t < TSTEPS; ++t){
        if (bid < BB){
            // ===== A1: w_ah cols [16*bid .. +16) for all 32 batches =====
            gwaitN(sH, 1, (unsigned)(t+1), &sfH);
            {
                int n0 = bid<<4;
                int kb = wave*64;               // K split 8x64
                floatx4 acc0 = {0,0,0,0}, acc1 = {0,0,0,0};
                const bf16* brow = Ww_bf + (size_t)(n0+lq)*HD;
                union U8 { unsigned u[4]; bf16x8 v; };
#pragma unroll
                for (int kk = 0; kk < 2; ++kk){
                    int k = kb + kk*32 + quad*8;
                    bf16x8 bfr = *(const bf16x8*)(brow + k);
                    U8 a0, a1;
                    const unsigned* ar0 = lin_u + (size_t)lq*(KCAT/2) + (EIN+k)/2;
                    const unsigned* ar1 = lin_u + (size_t)(16+lq)*(KCAT/2) + (EIN+k)/2;
#pragma unroll
                    for (int q = 0; q < 4; ++q){
                        a0.u[q] = coh_ld(ar0 + q);
                        a1.u[q] = coh_ld(ar1 + q);
                    }
                    acc0 = MFMA16(a0.v, bfr, acc0);
                    acc1 = MFMA16(a1.v, bfr, acc1);
                }
#pragma unroll
                for (int r = 0; r < 4; ++r){
                    red[wave][0][quad*4+r][lq] = acc0[r];
                    red[wave][1][quad*4+r][lq] = acc1[r];
                }
            }
            __syncthreads();
            {
                int b = tid>>4, c = tid&15;
                int mt = b>>4, mm = b&15;
                float s = 0.f;
#pragma unroll
                for (int w8 = 0; w8 < 8; ++w8) s += red[w8][mt][mm][c];
                int col = (bid<<4) + c;
                coh_st(wahu_u + (size_t)b*ATTD + col,
                       __float_as_uint(s + ld1(W_b, col, ff)));
            }
            gpost_slot(sW + bid, (unsigned)(t+1));
        }
        // ===== A23: scores+softmax (4x redundant) + ctx e-slice ============
        gwaitN(sW, 0, (unsigned)(t+1), &sfW);
        {
            const int b = bid>>2, sl = bid&3;
            wah_s[tid & 511] = __uint_as_float(coh_ld(wahu_u + (size_t)b*ATTD + (tid & 511)));
            __syncthreads();
            {
                int a0 = lane*8;
                for (int n = wave; n < NF; n += 8){
                    const float* up = u_hs + (size_t)(b*NF + n)*ATTD + a0;
                    float4 u0 = *(const float4*)up;
                    float4 u1 = *(const float4*)(up + 4);
                    float p0 = fast_tanh(u0.x + wah_s[a0+0])*aw_s[a0+0]
                             + fast_tanh(u0.y + wah_s[a0+1])*aw_s[a0+1]
                             + fast_tanh(u0.z + wah_s[a0+2])*aw_s[a0+2]
                             + fast_tanh(u0.w + wah_s[a0+3])*aw_s[a0+3];
                    float p1 = fast_tanh(u1.x + wah_s[a0+4])*aw_s[a0+4]
                             + fast_tanh(u1.y + wah_s[a0+5])*aw_s[a0+5]
                             + fast_tanh(u1.z + wah_s[a0+6])*aw_s[a0+6]
                             + fast_tanh(u1.w + wah_s[a0+7])*aw_s[a0+7];
                    float p = p0 + p1;
                    for (int off = 32; off; off >>= 1) p += __shfl_down(p, off);
                    if (lane == 0) sc_s[n] = p + ld1(A_b, 0, ff);
                }
            }
            __syncthreads();
            if (wave == 0){
                float v = (lane < NF) ? sc_s[lane] : -1e30f;
                float mx = v;
                for (int off = 32; off; off >>= 1) mx = fmaxf(mx, __shfl_down(mx, off));
                mx = __shfl(mx, 0);
                float e = (lane < NF) ? expf(v - mx) : 0.f;
                float s = e;
                for (int off = 32; off; off >>= 1) s += __shfl_down(s, off);
                s = __shfl(s, 0);
                if (lane < NF){
                    float al = e / s;
                    alpha_s[lane] = al;
                    if (sl == 0)
                        st1(d_out, (size_t)BB*TSTEPS*VCB + (size_t)b*(TSTEPS*NF) + t*NF + lane, al, ff);
                }
            }
            __syncthreads();
            if (tid < 256){
                int col = sl*512 + 2*tid;
                const bf16* fb = feat_bf + (size_t)b*NF*ENC + col;
                float a0 = 0.f, a1 = 0.f;
#pragma unroll 7
                for (int n = 0; n < NF; ++n){
                    unsigned fv = *(const unsigned*)(fb + (size_t)n*ENC);
                    float lo = __uint_as_float(fv << 16);
                    float hi = __uint_as_float(fv & 0xffff0000u);
                    float al = alpha_s[n];
                    a0 += al*lo; a1 += al*hi;
                }
                coh_st(lin_u + (size_t)b*(KCAT/2) + (EMB+col)/2, pack2bf(a0, a1));
            } else if (tid >= 448){
                int cap = captions[b*21 + t];
                int col = sl*128 + 2*(tid - 448);
                coh_st(lin_u + (size_t)b*(KCAT/2) + col/2,
                       pack2bf(ld1(emb, (size_t)cap*EMB + col,     ff),
                               ld1(emb, (size_t)cap*EMB + col + 1, ff)));
            }
            gpost_slot(sL + bid, (unsigned)(t+1));
        }
        gwaitN(sL, 1, (unsigned)(t+1), &sfL);

        // ===== B: gates MFMA (LDS wcat, 8-wave K-split) + LSTM pointwise ===
        {
            int kb = wave*384;                      // K split 8x384 over waves
            floatx4 acc0 = {0,0,0,0}, acc1 = {0,0,0,0};
            const bf16* wrow = wlds + (size_t)lq*WSTRIDE;  // 16 distinct B-rows
            const unsigned* ar0 = lin_u + (size_t)lq*(KCAT/2);
            const unsigned* ar1 = lin_u + (size_t)(16+lq)*(KCAT/2);
            union U8 { unsigned u[4]; bf16x8 v; };
#pragma unroll
            for (int kk = 0; kk < 12; ++kk){
                int kd = (kb + kk*32 + quad*8) >> 1;   // dword index
                bf16x8 bfr = *(const bf16x8*)(wrow + kb + kk*32 + quad*8);
                U8 a0, a1;
#pragma unroll
                for (int q = 0; q < 4; ++q){
                    a0.u[q] = coh_ld(ar0 + kd + q);
                    a1.u[q] = coh_ld(ar1 + kd + q);
                }
                acc0 = MFMA16(a0.v, bfr, acc0);
                acc1 = MFMA16(a1.v, bfr, acc1);
            }
#pragma unroll
            for (int r = 0; r < 4; ++r){
                red[wave][0][quad*4+r][lq] = acc0[r];
                red[wave][1][quad*4+r][lq] = acc1[r];
            }
        }
        __syncthreads();
        if (tid < 64){
            int bb = tid&31, j2 = tid>>5;           // j2: col pair 0/1
            int mt = bb>>4, mm = bb&15;
            float hn[2];
#pragma unroll
            for (int sub = 0; sub < 2; ++sub){
                int j = 2*j2 + sub;                 // col-in-block 0..3
                float G[4];
#pragma unroll
                for (int g = 0; g < 4; ++g){
                    int n = g*4 + j;                // B-row n = gate*4 + col
                    float s = 0.f;
#pragma unroll
                    for (int w8 = 0; w8 < 8; ++w8) s += red[w8][mt][mm][n];
                    G[g] = s + gbias[n];
                }
                float c_old = c_loc[bb*4+j];
                float c_new = sigm(G[1])*c_old + sigm(G[0])*tanhf(G[2]);
                float h_new = sigm(G[3])*tanhf(c_new);
                c_loc[bb*4+j] = c_new;
                hn[sub] = h_new;
            }
            int colb = (bid<<2) + 2*j2;
            ((unsigned*)Hall_bf)[((size_t)t*BB*HD + bb*HD + colb) >> 1] = pack2bf(hn[0], hn[1]);
            coh_st(lin_u + (size_t)bb*(KCAT/2) + (EIN + colb)/2, pack2bf(hn[0], hn[1]));
        }
        gpost_slot(sH + bid, (unsigned)(t+2));  // h(t+1) published
    }
}

// ---------------- kernel 6: preds = Hall_bf @ fcnw_bf^T + fcn_b ------------
__global__ void __launch_bounds__(256) k_fcn(const bf16* __restrict__ Hall_bf,
                                             const bf16* __restrict__ fcnw_bf,
                                             const void* fcn_b, void* d_out,
                                             const int* __restrict__ flag){
    int ff = *flag;
    int tid = threadIdx.x, wave = tid>>6, lane = tid&63, quad = lane>>4, lq = lane&15;
    int n0 = blockIdx.x*64 + wave*16;
    int v = n0 + lq;
    int vc = (v < VCB) ? v : (VCB-1);
    const bf16* brow = fcnw_bf + (size_t)vc*HD;
    bf16x8 bfr[16];
#pragma unroll
    for (int kk = 0; kk < 16; ++kk) bfr[kk] = *(const bf16x8*)(brow + kk*32 + quad*8);
    float bias = ld1(fcn_b, vc, ff);
    for (int mt = 0; mt < 40; ++mt){
        const bf16* arow = Hall_bf + (size_t)(mt*16 + lq)*HD;
        floatx4 acc = {0,0,0,0};
#pragma unroll
        for (int kk = 0; kk < 16; ++kk){
            bf16x8 afr = *(const bf16x8*)(arow + kk*32 + quad*8);
            acc = MFMA16(afr, bfr[kk], acc);
        }
        if (v < VCB){
#pragma unroll
            for (int r = 0; r < 4; ++r){
                int m = mt*16 + quad*4 + r;
                int b = m & 31, tt = m >> 5;
                st1(d_out, (size_t)b*(TSTEPS*VCB) + (size_t)tt*VCB + v, acc[r] + bias, ff);
            }
        }
    }
}

// ---------------- host launch ---------------------------------------------
extern "C" void kernel_launch(void* const* d_in, const int* in_sizes, int n_in,
                              void* d_out, int out_size, void* d_ws, size_t ws_size,
                              hipStream_t stream) {
    const void* feat  = d_in[0];
    const int*  caps  = (const int*)d_in[1];
    const void* emb   = d_in[2];
    const void* W_w   = d_in[3];
    const void* W_b   = d_in[4];
    const void* U_w   = d_in[5];
    const void* U_b   = d_in[6];
    const void* A_w   = d_in[7];
    const void* A_b   = d_in[8];
    const void* ihw   = d_in[9];
    const void* ihb   = d_in[10];
    const void* icw   = d_in[11];
    const void* icb   = d_in[12];
    const void* w_ih  = d_in[13];
    const void* w_hh  = d_in[14];
    const void* b_ih  = d_in[15];
    const void* b_hh  = d_in[16];
    const void* fcn_w = d_in[17];
    const void* fcn_b = d_in[18];

    // workspace layout (16B-aligned)
    char* ws = (char*)d_ws;
    size_t off = 0;
    float* u_hs    = (float*)(ws + off); off += (size_t)BB*NF*ATTD*4;       // 3.2 MB
    float* c_f32   = (float*)(ws + off); off += (size_t)BB*HD*4;            // 64 KB
    float* mean_f  = (float*)(ws + off); off += (size_t)BB*ENC*4;           // 256 KB
    float* Hbuf    = (float*)(ws + off); off += (size_t)(TSTEPS+1)*BB*HD*4; // 1.38 MB
    bf16*  lstm_in = (bf16*) (ws + off); off += (size_t)BB*KCAT*2;          // 192 KB
    bf16*  Hall_bf = (bf16*) (ws + off); off += (size_t)TSTEPS*BB*HD*2;     // 640 KB
    bf16*  wcat    = (bf16*) (ws + off); off += (size_t)4*HD*KCAT*2;        // 12.6 MB
    bf16*  fcnw_bf = (bf16*) (ws + off); off += (size_t)VCB*HD*2;           // 31.25 MB
    bf16*  Ww_bf   = (bf16*) (ws + off); off += (size_t)ATTD*HD*2;          // 512 KB
    bf16*  feat_bf = (bf16*) (ws + off); off += (size_t)BB*NF*ENC*2;        // 6.4 MB
    float* wah_u   = (float*)(ws + off); off += (size_t)BB*ATTD*4;          // 64 KB
    int*   flag    = (int*)  (ws + off); off += 256;
    unsigned* bar  = (unsigned*)(ws + off); off += 4096;
    if (ws_size < off) return;

    k_detect    <<<1, 256, 0, stream>>>(emb, flag, bar);
    k_prep_gates<<<2048, 256, 0, stream>>>(w_ih, w_hh, wcat, flag);
    k_prep_cvt8 <<<2048, 256, 0, stream>>>(fcn_w, fcnw_bf, (size_t)VCB*HD/8, flag);
    k_prep_cvt8 <<<128, 256, 0, stream>>>(W_w, Ww_bf, (size_t)ATTD*HD/8, flag);
    k_prep_cvt8 <<<1024, 256, 0, stream>>>(feat, feat_bf, (size_t)BB*NF*ENC/8, flag);
    k_mean      <<<BB, 256, 0, stream>>>(feat, mean_f, flag);
    k_init_hc   <<<64, 256, 0, stream>>>(mean_f, ihw, ihb, icw, icb, Hbuf, c_f32, flag);
    k_uhs       <<<dim3(98, 8), 256, 0, stream>>>(feat_bf, U_w, U_b, u_hs, flag);

    // whole 20-step decode loop in one cooperative launch (3 slot-syncs/step)
    {
        void* kargs[19] = {
            (void*)&Hbuf, (void*)&c_f32, (void*)&Ww_bf, (void*)&W_b,
            (void*)&u_hs, (void*)&A_w, (void*)&A_b, (void*)&caps,
            (void*)&emb, (void*)&feat_bf, (void*)&lstm_in, (void*)&wcat,
            (void*)&b_ih, (void*)&b_hh, (void*)&Hall_bf, (void*)&d_out,
            (void*)&flag, (void*)&bar, (void*)&wah_u
        };
        hipLaunchCooperativeKernel((void*)k_decode, dim3(NBLK), dim3(DTPB),
                                   kargs, 0, stream);
    }

    k_fcn<<<477, 256, 0, stream>>>(Hall_bf, fcnw_bf, fcn_b, d_out, flag);
}